// Round 13
// baseline (512.590 us; speedup 1.0000x reference)
//
#include <hip/hip_runtime.h>
#include <hip/hip_bf16.h>

#define T_FR 2
#define C_CH 32
#define H_IMG 224
#define W_IMG 336
#define NH 4
#define NPATCH 1176
#define NQ 2352
#define NPAD 2432
#define DD 2048
#define WOUT (W_IMG*NH)
#define SM_SCALE 0.6629126073623885f   // 30/sqrt(2048)
#define PIX_F (H_IMG*W_IMG)            // 75264
#define PIX_T (T_FR*PIX_F)             // 150528

typedef __attribute__((ext_vector_type(4))) float f32x4;
typedef __attribute__((ext_vector_type(8))) short short8;
typedef unsigned short ushort_t;
typedef __attribute__((ext_vector_type(4))) unsigned short u16x4;
typedef __attribute__((ext_vector_type(8))) unsigned short u16x8;

__device__ inline ushort_t f2bf(float x){
  union { float f; unsigned int u; } v; v.f = x;
  unsigned int r = v.u + 0x7fffu + ((v.u >> 16) & 1u);
  return (ushort_t)(r >> 16);
}

__device__ inline void gload16(const void* g, void* l){
  __builtin_amdgcn_global_load_lds(
      (const __attribute__((address_space(1))) void*)g,
      (__attribute__((address_space(3))) void*)l,
      16, 0, 0);
}

// ---------------- zero pad rows [NQ,NPAD) of Qu/Ku/Vu ----------------------
__global__ __launch_bounds__(256) void zero_pads(
    ushort_t* __restrict__ Qu, ushort_t* __restrict__ Ku,
    ushort_t* __restrict__ Vu, int nh)
{
  const int per = 80*DD;
  int tot = 3*nh*per;
  for (int id = blockIdx.x*256 + threadIdx.x; id < tot; id += gridDim.x*256){
    int buf = id / (nh*per);
    int rem = id - buf*(nh*per);
    int h = rem / per;
    int e = rem - h*per;
    ushort_t* B = (buf==0) ? Qu : (buf==1) ? Ku : Vu;
    B[((size_t)h*NPAD + NQ)*DD + e] = 0;
  }
}

// ------------- value input -> channels-last bf16 [PIX_T][32] ---------------
__global__ __launch_bounds__(256) void transpose_cl(
    const float* __restrict__ in, ushort_t* __restrict__ inCL)
{
  int id = blockIdx.x*256 + threadIdx.x;   // 150528 exactly
  int t = id / PIX_F;
  int p = id - t*PIX_F;
  const float* src = in + (size_t)t*C_CH*PIX_F + p;
  #pragma unroll
  for (int oct=0; oct<4; oct++){
    u16x8 u;
    #pragma unroll
    for (int e=0; e<8; e++)
      u[e] = f2bf(src[(size_t)(oct*8+e)*PIX_F]);
    *(u16x8*)&inCL[(size_t)id*C_CH + oct*8] = u;
  }
}

// ------------- V weights -> bf16 Wb[tap][o_global 128][cc 32] --------------
__global__ __launch_bounds__(256) void prep_wb(
    const float* __restrict__ Wv, ushort_t* __restrict__ Wb)
{
  int idx = blockIdx.x*256 + threadIdx.x;   // 36864 exactly
  if (idx >= 9*128*32) return;
  int tap = idx >> 12;
  int og  = (idx >> 5) & 127;
  int cc  = idx & 31;
  Wb[idx] = f2bf(Wv[(size_t)og*288 + cc*9 + tap]);
}

// ------ depthwise 3x3 conv + unfold, ALL heads per thread (input read 1x) --
__global__ __launch_bounds__(256) void dwconv_unfold(
    const float* __restrict__ in, const float* __restrict__ Wd,
    const float* __restrict__ bd, ushort_t* __restrict__ outU,
    int head0, int nh)
{
  int id = blockIdx.x*256 + threadIdx.x;       // 602112 total
  int cc = id & 31;
  int rest = id >> 5;
  int xseg = rest % 42;
  rest /= 42;
  int y = rest % H_IMG;
  int t = rest / H_IMG;

  const float* src = in + ((size_t)(t*C_CH + cc)*H_IMG)*W_IMG;
  int x0 = xseg*8;

  float r0[10], r1[10], r2[10];
  #pragma unroll
  for (int j=0;j<10;j++){
    int xx = x0 + j - 1;
    bool xok = (xx>=0) && (xx<W_IMG);
    r0[j] = (xok && y>0)         ? src[(size_t)(y-1)*W_IMG+xx] : 0.f;
    r1[j] = (xok)                ? src[(size_t)y*W_IMG+xx]     : 0.f;
    r2[j] = (xok && y<H_IMG-1)   ? src[(size_t)(y+1)*W_IMG+xx] : 0.f;
  }
  int qrow = t*NPATCH + (y>>3)*42 + xseg;
  int dcol = (y&7)*256 + cc*8;

  for (int h = 0; h < nh; ++h){
    const float* w = Wd + ((size_t)(head0+h)*C_CH + cc)*9;
    float w0=w[0],w1=w[1],w2=w[2],w3=w[3],w4=w[4],w5=w[5],w6=w[6],w7=w[7],w8=w[8];
    float bias = bd[(size_t)(head0+h)*C_CH + cc];
    u16x8 res;
    #pragma unroll
    for (int j=0;j<8;j++){
      float a = bias;
      a += r0[j]*w0 + r0[j+1]*w1 + r0[j+2]*w2;
      a += r1[j]*w3 + r1[j+1]*w4 + r1[j+2]*w5;
      a += r2[j]*w6 + r2[j+1]*w7 + r2[j+2]*w8;
      res[j] = f2bf(a);
    }
    *(u16x8*)&outU[((size_t)h*NPAD + qrow)*DD + dcol] = res;
  }
}

// --------- dense V conv as implicit MFMA GEMM + coalesced Vu write ---------
#define VA_HALO 0
#define VA_BS   37120
#define V_LDS   73984

__global__ __launch_bounds__(256) void vconv_mfma(
    const ushort_t* __restrict__ inCL, const ushort_t* __restrict__ Wb,
    const float* __restrict__ bvv, ushort_t* __restrict__ Vu, int head0)
{
  __shared__ __align__(16) char lds[V_LDS];
  int xt = blockIdx.x;
  int pr_g = blockIdx.y;
  int z  = blockIdx.z;
  int t  = pr_g / 28, pr = pr_g - t*28;
  int x0 = xt*56, y0 = pr*8;
  int tid = threadIdx.x, lane = tid & 63, wid = tid >> 6;

  for (int i = tid; i < 580; i += 256){
    int ly = i/58, lx = i - (i/58)*58;
    int gy = y0 - 1 + ly, gx = x0 - 1 + lx;
    u16x8 v0={},v1={},v2={},v3={};
    if (gy>=0 && gy<H_IMG && gx>=0 && gx<W_IMG){
      const u16x8* s = (const u16x8*)&inCL[((size_t)t*PIX_F + gy*W_IMG + gx)*C_CH];
      v0=s[0]; v1=s[1]; v2=s[2]; v3=s[3];
    }
    *(u16x8*)&lds[VA_HALO + 0*9280 + i*16] = v0;
    *(u16x8*)&lds[VA_HALO + 1*9280 + i*16] = v1;
    *(u16x8*)&lds[VA_HALO + 2*9280 + i*16] = v2;
    *(u16x8*)&lds[VA_HALO + 3*9280 + i*16] = v3;
  }
  for (int i = tid; i < 576; i += 256){
    int tap = i/64, ol = i - (i/64)*64;
    const u16x8* s = (const u16x8*)&Wb[((size_t)tap*128 + head0*32 + z*64 + ol)*C_CH];
    #pragma unroll
    for (int oct=0; oct<4; oct++)
      *(u16x8*)&lds[VA_BS + tap*4096 + ol*64 + ((oct^(ol&3))<<4)] = s[oct];
  }
  __syncthreads();

  int aoff[7];
  #pragma unroll
  for (int m=0;m<7;m++){
    int pm = wid*112 + m*16 + (lane&15);
    int yl = pm/56, xl = pm - yl*56;
    aoff[m] = VA_HALO + (lane>>4)*9280 + (yl*58 + xl)*16;
  }

  f32x4 acc[7][4] = {};
  #pragma unroll
  for (int tap=0; tap<9; tap++){
    const int dy = tap/3, dx = tap - (tap/3)*3;
    short8 bfr[4];
    #pragma unroll
    for (int n=0;n<4;n++){
      int ol = n*16 + (lane&15);
      bfr[n] = *(const short8*)&lds[VA_BS + tap*4096 + ol*64 + ((((lane>>4))^(ol&3))<<4)];
    }
    #pragma unroll
    for (int m=0;m<7;m++){
      short8 af = *(const short8*)&lds[aoff[m] + (dy*58+dx)*16];
      #pragma unroll
      for (int n=0;n<4;n++)
        acc[m][n] = __builtin_amdgcn_mfma_f32_16x16x32_bf16(af, bfr[n], acc[m][n], 0,0,0);
    }
  }
  __syncthreads();

  float bias[4];
  #pragma unroll
  for (int n=0;n<4;n++){
    int ol = n*16 + (lane&15);
    bias[n] = bvv[(size_t)(head0 + z*2 + (ol>>5))*C_CH + (ol&31)];
  }
  #pragma unroll
  for (int m=0;m<7;m++){
    #pragma unroll
    for (int j=0;j<4;j++){
      int p = wid*112 + m*16 + (lane>>4)*4 + j;
      int yl = p/56, xl = p - (p/56)*56;
      int kl = xl >> 3;
      int off = yl*8 + (xl&7);
      #pragma unroll
      for (int n=0;n<4;n++){
        int ol = n*16 + (lane&15);
        int addr = ((ol>>5)*7 + kl)*4096 + (off*32 + (ol&31))*2;
        *(ushort_t*)&lds[addr] = f2bf(acc[m][n][j] + bias[n]);
      }
    }
  }
  __syncthreads();
  int key0 = t*NPATCH + pr*42 + xt*7;
  #pragma unroll
  for (int i=0;i<14;i++){
    int c = i*256 + tid;
    int hib = c / 1792;
    int rem = c - hib*1792;
    int kl = rem >> 8, dch = rem & 255;
    u16x8 v = *(const u16x8*)&lds[c*16];
    *(u16x8*)&Vu[((size_t)(z*2+hib)*NPAD + key0 + kl)*DD + dch*8] = v;
  }
}

// --------- Vu [head][key][dd'] -> Vt [head][dd'][key] ----------------------
__global__ __launch_bounds__(256) void vtranspose(
    const ushort_t* __restrict__ Vu, ushort_t* __restrict__ Vt)
{
  __shared__ ushort_t tile[64*68];
  int d0 = blockIdx.x*64;
  int k0 = blockIdx.y*64;
  const ushort_t* src = Vu + (size_t)blockIdx.z*NPAD*DD;
  ushort_t* dst = Vt + (size_t)blockIdx.z*DD*NPAD;
  int t = threadIdx.x;
  #pragma unroll
  for (int i=0;i<2;i++){
    int key = (t>>3) + i*32;
    int dd  = (t&7)*8;
    u16x8 v = *(const u16x8*)&src[(size_t)(k0+key)*DD + d0+dd];
    #pragma unroll
    for (int e=0;e<8;e++) tile[(dd+e)*68 + key] = v[e];
  }
  __syncthreads();
  #pragma unroll
  for (int i=0;i<2;i++){
    int dd  = (t>>3) + i*32;
    int key = (t&7)*8;
    u16x4 a = *(const u16x4*)&tile[dd*68 + key];
    u16x4 b = *(const u16x4*)&tile[dd*68 + key + 4];
    u16x8 v;
    v[0]=a[0]; v[1]=a[1]; v[2]=a[2]; v[3]=a[3];
    v[4]=b[0]; v[5]=b[1]; v[6]=b[2]; v[7]=b[3];
    *(u16x8*)&dst[(size_t)(d0+dd)*NPAD + k0+key] = v;
  }
}

// ===== 256x256 GEMM, BK=32, 2-buffer 64KB LDS -> 2 blocks/CU co-resident ====
// B^T GEMM: C[row][col] = sum_k A[row][k]*B[col][k].
// 512 thr = 8 waves (2M x 4N), wave tile 128x64. NT = K/32 tiles.
// LDS 64KB: A[2][256x32] + B[2][256x32] (16KB regions).
// Tile t: ph1 {RD af(mh0)+bf; stage tile t+1 (A+B, 4 loads); bar; 16 MFMA; bar}
//         ph2 {RD ag(mh1); bar; 16 MFMA; vmcnt(0) gate + bar}
// 2 blocks/CU: gate stall of one block hides under the other's MFMA; grids
// 400/320 blocks <= 512 slots -> zero dispatch tail.
#define ABASE2(b) ((b)*16384)
#define BBASE2(b) (32768 + (b)*16384)

#define STG(dstb, Mat, t0, Rm1, ktc) { \
  int i0_ = tid;       int r0_ = i0_>>2; int c0_ = ((i0_&3) ^ ((r0_>>1)&3)); \
  gload16(Mat + (size_t)min(t0 + r0_, Rm1)*(size_t)K + (ktc) + c0_*8, \
          lds + (dstb) + (tid & ~63)*16); \
  int i1_ = 512 + tid; int r1_ = i1_>>2; int c1_ = ((i1_&3) ^ ((r1_>>1)&3)); \
  gload16(Mat + (size_t)min(t0 + r1_, Rm1)*(size_t)K + (ktc) + c1_*8, \
          lds + (dstb) + (512 + (tid & ~63))*16); }

#define RD_A(dst, b, mh) { _Pragma("unroll") \
  for (int m=0;m<4;m++) \
    dst[m] = *(const short8*)(lds + ABASE2(b) + (wr*128 + (mh)*64 + m*16 + l15)*64 + rkB); }

#define RD_B(dst, b) { _Pragma("unroll") \
  for (int n=0;n<4;n++) \
    dst[n] = *(const short8*)(lds + BBASE2(b) + (wc*64 + n*16 + l15)*64 + rkB); }

#define DO_MFMA(afS, bfS, mh) { __builtin_amdgcn_s_setprio(1); \
  _Pragma("unroll") for (int m=0;m<4;m++){ \
    _Pragma("unroll") for (int n=0;n<4;n++) \
      acc[(mh)*4+m][n] = __builtin_amdgcn_mfma_f32_16x16x32_bf16(afS[m], bfS[n], acc[(mh)*4+m][n], 0,0,0); } \
  __builtin_amdgcn_s_setprio(0); }

#define BAR() { __builtin_amdgcn_sched_barrier(0); \
  __builtin_amdgcn_s_barrier(); __builtin_amdgcn_sched_barrier(0); }

#define GATE0() { __builtin_amdgcn_sched_barrier(0); \
  asm volatile("s_waitcnt vmcnt(0)" ::: "memory"); \
  __builtin_amdgcn_s_barrier(); __builtin_amdgcn_sched_barrier(0); }

template<int MODE>
__global__ __launch_bounds__(512) void gemm8p(
    const ushort_t* __restrict__ A, const ushort_t* __restrict__ B,
    float* __restrict__ C, float* __restrict__ Out,
    int K, int Am1, int Bm1, size_t aStr, size_t bStr, int head0)
{
  __shared__ __align__(16) char lds[65536];
  int tid = threadIdx.x, lane = tid & 63, wid = tid >> 6;

  // bijective XCD swizzle (nwg % 8 == 0 for both grids)
  int gx = gridDim.x, gy = gridDim.y;
  int nwg = gx*gy*gridDim.z;
  int id  = (blockIdx.z*gy + blockIdx.y)*gx + blockIdx.x;
  int swz = (id & 7)*(nwg >> 3) + (id >> 3);
  int bx = swz % gx; int tmp = swz / gx;
  int by = tmp % gy; int bz = tmp / gy;

  const ushort_t* Ab = A + (size_t)bz*aStr;
  const ushort_t* Bb = B + (size_t)bz*bStr;
  int row0 = by*256, col0 = bx*256;
  int wr = wid >> 2, wc = wid & 3;           // 2M x 4N waves; wave = 128M x 64N
  int l15 = lane & 15;
  int rkB = (((lane>>4) ^ ((l15>>1)&3)) * 16);

  f32x4 acc[8][4] = {};
  int NT = K >> 5;          // BK=32 tiles (64 or 76)

  // prologue: stage T0 into buf0; prove landed
  STG(ABASE2(0), Ab, row0, Am1, 0)
  STG(BBASE2(0), Bb, col0, Bm1, 0)
  __builtin_amdgcn_sched_barrier(0);
  asm volatile("s_waitcnt vmcnt(0)" ::: "memory");
  __builtin_amdgcn_s_barrier();
  __builtin_amdgcn_sched_barrier(0);

  #pragma unroll 1
  for (int t = 0; t < NT; ++t){
    int b = t & 1, nb = b ^ 1;
    bool more = (t + 1 < NT);
    short8 af[4], ag[4], bf[4];

    // ph1: read mh0 frags + B frags of buf b; stage tile t+1 into buf nb
    // (buf nb's last reads were consumed before tile t-1's final barrier)
    RD_A(af, b, 0) RD_B(bf, b)
    if (more){
      int ktn = (t+1) << 5;
      STG(ABASE2(nb), Ab, row0, Am1, ktn)
      STG(BBASE2(nb), Bb, col0, Bm1, ktn)
    }
    BAR()
    DO_MFMA(af, bf, 0)
    BAR()
    // ph2: read mh1 frags (buf b still live); gate proves tile t+1 landed
    RD_A(ag, b, 1)
    BAR()
    DO_MFMA(ag, bf, 1)
    GATE0()
  }
  __builtin_amdgcn_sched_barrier(0);
  asm volatile("s_waitcnt vmcnt(0) lgkmcnt(0)" ::: "memory");
  __builtin_amdgcn_sched_barrier(0);

  int rb0 = row0 + wr*128 + (lane>>4)*4;
  int cb0 = col0 + wc*64 + l15;
  if (MODE == 0){
    float* Cb = C + (size_t)bz*NPAD*(size_t)NPAD;
    #pragma unroll
    for (int M=0;M<8;M++)
      #pragma unroll
      for (int n=0;n<4;n++){
        int col = cb0 + n*16;
        if (col < NPAD)
          #pragma unroll
          for (int j=0;j<4;j++){
            int row = rb0 + M*16 + j;
            if (row < NPAD)
              Cb[(size_t)row*NPAD + col] = acc[M][n][j];
          }
      }
  } else {
    int head = head0 + bz;
    #pragma unroll
    for (int M=0;M<8;M++){
      #pragma unroll
      for (int j=0;j<4;j++){
        int q = rb0 + M*16 + j;
        if (q < NQ){
          int t = q / NPATCH;
          int p = q - t*NPATCH;
          int hi = p / 42, wi = p - hi*42;
          #pragma unroll
          for (int n=0;n<4;n++){
            int dd = cb0 + n*16;            // dd' = (pi*8+pj)*32 + cch
            int cch = dd & 31;
            int off = dd >> 5;
            int pi = off >> 3, pj = off & 7;
            int yy = hi*8 + pi, xx = wi*8 + pj;
            Out[(((size_t)t*C_CH + cch)*H_IMG + yy)*WOUT + (size_t)head*W_IMG + xx]
              = acc[M][n][j];
          }
        }
      }
    }
  }
}

// ------------- row softmax: S f32 -> P bf16 (vectorized, G13) ---------------
__global__ __launch_bounds__(256) void softmax_rows(
    const float* __restrict__ S, ushort_t* __restrict__ Pm)
{
  const float* row = S + ((size_t)blockIdx.y*NPAD + blockIdx.x)*NPAD;
  ushort_t* prow = Pm + ((size_t)blockIdx.y*NPAD + blockIdx.x)*NPAD;
  int tid = threadIdx.x;
  __shared__ float red[4];
  const f32x4* row4 = (const f32x4*)row;

  bool h2 = (512 + tid) < 588;
  f32x4 v0 = row4[tid];
  f32x4 v1 = row4[256 + tid];
  f32x4 v2 = {-3.0e38f, -3.0e38f, -3.0e38f, -3.0e38f};
  if (h2) v2 = row4[512 + tid];

  float mx = -3.0e38f;
  #pragma unroll
  for (int e=0;e<4;e++) mx = fmaxf(mx, fmaxf(v0[e], fmaxf(v1[e], v2[e])));
  #pragma unroll
  for (int o=32;o;o>>=1) mx = fmaxf(mx, __shfl_xor(mx, o));
  if ((tid&63)==0) red[tid>>6] = mx;
  __syncthreads();
  mx = fmaxf(fmaxf(red[0],red[1]), fmaxf(red[2],red[3]));
  __syncthreads();

  f32x4 e0, e1, e2 = {0.f,0.f,0.f,0.f};
  float s = 0.f;
  #pragma unroll
  for (int e=0;e<4;e++){ e0[e] = __expf((v0[e]-mx)*SM_SCALE); s += e0[e]; }
  #pragma unroll
  for (int e=0;e<4;e++){ e1[e] = __expf((v1[e]-mx)*SM_SCALE); s += e1[e]; }
  if (h2){
    #pragma unroll
    for (int e=0;e<4;e++){ e2[e] = __expf((v2[e]-mx)*SM_SCALE); s += e2[e]; }
  }
  #pragma unroll
  for (int o=32;o;o>>=1) s += __shfl_xor(s, o);
  if ((tid&63)==0) red[tid>>6] = s;
  __syncthreads();
  s = (red[0]+red[1]) + (red[2]+red[3]);
  float inv = 1.0f / s;

  u16x4 o0, o1;
  #pragma unroll
  for (int e=0;e<4;e++) o0[e] = f2bf(e0[e]*inv);
  #pragma unroll
  for (int e=0;e<4;e++) o1[e] = f2bf(e1[e]*inv);
  *(u16x4*)&prow[tid*4]        = o0;
  *(u16x4*)&prow[1024 + tid*4] = o1;
  if (h2){
    u16x4 o2;
    #pragma unroll
    for (int e=0;e<4;e++) o2[e] = f2bf(e2[e]*inv);
    *(u16x4*)&prow[2048 + tid*4] = o2;
  } else if (512 + tid < 608){
    u16x4 z = {0,0,0,0};
    *(u16x4*)&prow[2048 + tid*4] = z;   // pad cols 2352..2431
  }
}

// ------------------------------------------------------------------ host ----
extern "C" void kernel_launch(void* const* d_in, const int* in_sizes, int n_in,
                              void* d_out, int out_size, void* d_ws, size_t ws_size,
                              hipStream_t stream)
{
  const float* query = (const float*)d_in[0];
  const float* key_  = (const float*)d_in[1];
  const float* value = (const float*)d_in[2];
  const float* Wq = (const float*)d_in[3];
  const float* bq = (const float*)d_in[4];
  const float* Wk = (const float*)d_in[5];
  const float* bk = (const float*)d_in[6];
  const float* Wv = (const float*)d_in[7];
  const float* bv = (const float*)d_in[8];
  float* out = (float*)d_out;

  const size_t szU = (size_t)NPAD*DD;
  const size_t szS = (size_t)NPAD*NPAD;
  const size_t perHeadB = 3*szU*sizeof(ushort_t) + szS*sizeof(float) + szS*sizeof(ushort_t);

  int nh = (ws_size >= 4*perHeadB) ? 4 : 2;

  for (int h0 = 0; h0 < NH; h0 += nh){
    char* p = (char*)d_ws;
    ushort_t* Qu = (ushort_t*)p; p += nh*szU*sizeof(ushort_t);
    ushort_t* Ku = (ushort_t*)p; p += nh*szU*sizeof(ushort_t);
    ushort_t* Vu = (ushort_t*)p; p += nh*szU*sizeof(ushort_t);
    float*    S  = (float*)p;    p += nh*szS*sizeof(float);
    ushort_t* Pm = (ushort_t*)p;
    ushort_t* inCL = (ushort_t*)S;                 // S region dead until gemm_qk
    ushort_t* Wb   = inCL + (size_t)PIX_T*C_CH;
    ushort_t* Vt   = Qu;                           // Qu dead after gemm_qk

    zero_pads<<<dim3(960), dim3(256), 0, stream>>>(Qu, Ku, Vu, nh);
    transpose_cl<<<dim3(588), dim3(256), 0, stream>>>(value, inCL);
    prep_wb<<<dim3(144), dim3(256), 0, stream>>>(Wv, Wb);
    dwconv_unfold<<<dim3(2352), dim3(256), 0, stream>>>(query, Wq, bq, Qu, h0, nh);
    dwconv_unfold<<<dim3(2352), dim3(256), 0, stream>>>(key_,  Wk, bk, Ku, h0, nh);
    vconv_mfma<<<dim3(6, 56, nh/2), dim3(256), 0, stream>>>(inCL, Wb, bv, Vu, h0);
    // QK^T: A=Qu, B=Ku, K=DD; grid 10x10x4 = 400 (%8==0)
    gemm8p<0><<<dim3(10, 10, nh), dim3(512), 0, stream>>>(
        Qu, Ku, S, nullptr, DD, NPAD-1, NPAD-1, szU, szU, h0);
    vtranspose<<<dim3(32, 38, nh), dim3(256), 0, stream>>>(Vu, Vt);
    softmax_rows<<<dim3(NPAD, nh), dim3(256), 0, stream>>>(S, Pm);
    // PV: A=Pm [NPAD][NPAD], B=Vt [DD][NPAD], K=NPAD; grid 8x10x4 = 320
    gemm8p<1><<<dim3(8, 10, nh), dim3(512), 0, stream>>>(
        Pm, Vt, nullptr, out, NPAD, NPAD-1, DD-1, szS, szU, h0);
  }
}

// Round 14
// 473.778 us; speedup vs baseline: 1.0819x; 1.0819x over previous
//
#include <hip/hip_runtime.h>
#include <hip/hip_bf16.h>

#define T_FR 2
#define C_CH 32
#define H_IMG 224
#define W_IMG 336
#define NH 4
#define NPATCH 1176
#define NQ 2352
#define NPAD 2432
#define DD 2048
#define WOUT (W_IMG*NH)
#define SM_SCALE 0.6629126073623885f   // 30/sqrt(2048)
#define PIX_F (H_IMG*W_IMG)            // 75264
#define PIX_T (T_FR*PIX_F)             // 150528

typedef __attribute__((ext_vector_type(4))) float f32x4;
typedef __attribute__((ext_vector_type(8))) short short8;
typedef unsigned short ushort_t;
typedef __attribute__((ext_vector_type(4))) unsigned short u16x4;
typedef __attribute__((ext_vector_type(8))) unsigned short u16x8;

__device__ inline ushort_t f2bf(float x){
  union { float f; unsigned int u; } v; v.f = x;
  unsigned int r = v.u + 0x7fffu + ((v.u >> 16) & 1u);
  return (ushort_t)(r >> 16);
}

__device__ inline void gload16(const void* g, void* l){
  __builtin_amdgcn_global_load_lds(
      (const __attribute__((address_space(1))) void*)g,
      (__attribute__((address_space(3))) void*)l,
      16, 0, 0);
}

// ---- merged prep: V->channels-last bf16 | Wv->Wb bf16 | Vu pad-row zero ----
// region sizes are exact multiples of 256 -> no intra-block divergence.
__global__ __launch_bounds__(256) void prep_all(
    const float* __restrict__ value, const float* __restrict__ Wv,
    ushort_t* __restrict__ inCL, ushort_t* __restrict__ Wb,
    ushort_t* __restrict__ Vu, int nh)
{
  int id = blockIdx.x*256 + threadIdx.x;
  if (id < PIX_T){
    int t = id / PIX_F;
    int p = id - t*PIX_F;
    const float* src = value + (size_t)t*C_CH*PIX_F + p;
    #pragma unroll
    for (int oct=0; oct<4; oct++){
      u16x8 u;
      #pragma unroll
      for (int e=0; e<8; e++)
        u[e] = f2bf(src[(size_t)(oct*8+e)*PIX_F]);
      *(u16x8*)&inCL[(size_t)id*C_CH + oct*8] = u;
    }
    return;
  }
  id -= PIX_T;
  if (id < 9*128*32){
    int tap = id >> 12;
    int og  = (id >> 5) & 127;
    int cc  = id & 31;
    Wb[id] = f2bf(Wv[(size_t)og*288 + cc*9 + tap]);
    return;
  }
  id -= 9*128*32;
  const int perH = 80*DD/8;                 // 20480 u16x8 items per head
  if (id < nh*perH){
    int h = id / perH;
    int e = id - h*perH;
    u16x8 z = {0,0,0,0,0,0,0,0};
    *(u16x8*)&Vu[((size_t)h*NPAD + NQ)*DD + (size_t)e*8] = z;
  }
}

// ------ depthwise 3x3 conv + unfold, ALL heads per thread (input read 1x) --
__global__ __launch_bounds__(256) void dwconv_unfold(
    const float* __restrict__ in, const float* __restrict__ Wd,
    const float* __restrict__ bd, ushort_t* __restrict__ outU,
    int head0, int nh)
{
  int id = blockIdx.x*256 + threadIdx.x;       // 602112 total
  int cc = id & 31;
  int rest = id >> 5;
  int xseg = rest % 42;
  rest /= 42;
  int y = rest % H_IMG;
  int t = rest / H_IMG;

  const float* src = in + ((size_t)(t*C_CH + cc)*H_IMG)*W_IMG;
  int x0 = xseg*8;

  float r0[10], r1[10], r2[10];
  #pragma unroll
  for (int j=0;j<10;j++){
    int xx = x0 + j - 1;
    bool xok = (xx>=0) && (xx<W_IMG);
    r0[j] = (xok && y>0)         ? src[(size_t)(y-1)*W_IMG+xx] : 0.f;
    r1[j] = (xok)                ? src[(size_t)y*W_IMG+xx]     : 0.f;
    r2[j] = (xok && y<H_IMG-1)   ? src[(size_t)(y+1)*W_IMG+xx] : 0.f;
  }
  int qrow = t*NPATCH + (y>>3)*42 + xseg;
  int dcol = (y&7)*256 + cc*8;

  for (int h = 0; h < nh; ++h){
    const float* w = Wd + ((size_t)(head0+h)*C_CH + cc)*9;
    float w0=w[0],w1=w[1],w2=w[2],w3=w[3],w4=w[4],w5=w[5],w6=w[6],w7=w[7],w8=w[8];
    float bias = bd[(size_t)(head0+h)*C_CH + cc];
    u16x8 res;
    #pragma unroll
    for (int j=0;j<8;j++){
      float a = bias;
      a += r0[j]*w0 + r0[j+1]*w1 + r0[j+2]*w2;
      a += r1[j]*w3 + r1[j+1]*w4 + r1[j+2]*w5;
      a += r2[j]*w6 + r2[j+1]*w7 + r2[j+2]*w8;
      res[j] = f2bf(a);
    }
    *(u16x8*)&outU[((size_t)h*NPAD + qrow)*DD + dcol] = res;
  }
}

// --------- dense V conv as implicit MFMA GEMM + coalesced Vu write ---------
#define VA_HALO 0
#define VA_BS   37120
#define V_LDS   73984

__global__ __launch_bounds__(256) void vconv_mfma(
    const ushort_t* __restrict__ inCL, const ushort_t* __restrict__ Wb,
    const float* __restrict__ bvv, ushort_t* __restrict__ Vu, int head0)
{
  __shared__ __align__(16) char lds[V_LDS];
  int xt = blockIdx.x;
  int pr_g = blockIdx.y;
  int z  = blockIdx.z;
  int t  = pr_g / 28, pr = pr_g - t*28;
  int x0 = xt*56, y0 = pr*8;
  int tid = threadIdx.x, lane = tid & 63, wid = tid >> 6;

  for (int i = tid; i < 580; i += 256){
    int ly = i/58, lx = i - (i/58)*58;
    int gy = y0 - 1 + ly, gx = x0 - 1 + lx;
    u16x8 v0={},v1={},v2={},v3={};
    if (gy>=0 && gy<H_IMG && gx>=0 && gx<W_IMG){
      const u16x8* s = (const u16x8*)&inCL[((size_t)t*PIX_F + gy*W_IMG + gx)*C_CH];
      v0=s[0]; v1=s[1]; v2=s[2]; v3=s[3];
    }
    *(u16x8*)&lds[VA_HALO + 0*9280 + i*16] = v0;
    *(u16x8*)&lds[VA_HALO + 1*9280 + i*16] = v1;
    *(u16x8*)&lds[VA_HALO + 2*9280 + i*16] = v2;
    *(u16x8*)&lds[VA_HALO + 3*9280 + i*16] = v3;
  }
  for (int i = tid; i < 576; i += 256){
    int tap = i/64, ol = i - (i/64)*64;
    const u16x8* s = (const u16x8*)&Wb[((size_t)tap*128 + head0*32 + z*64 + ol)*C_CH];
    #pragma unroll
    for (int oct=0; oct<4; oct++)
      *(u16x8*)&lds[VA_BS + tap*4096 + ol*64 + ((oct^(ol&3))<<4)] = s[oct];
  }
  __syncthreads();

  int aoff[7];
  #pragma unroll
  for (int m=0;m<7;m++){
    int pm = wid*112 + m*16 + (lane&15);
    int yl = pm/56, xl = pm - yl*56;
    aoff[m] = VA_HALO + (lane>>4)*9280 + (yl*58 + xl)*16;
  }

  f32x4 acc[7][4] = {};
  #pragma unroll
  for (int tap=0; tap<9; tap++){
    const int dy = tap/3, dx = tap - (tap/3)*3;
    short8 bfr[4];
    #pragma unroll
    for (int n=0;n<4;n++){
      int ol = n*16 + (lane&15);
      bfr[n] = *(const short8*)&lds[VA_BS + tap*4096 + ol*64 + ((((lane>>4))^(ol&3))<<4)];
    }
    #pragma unroll
    for (int m=0;m<7;m++){
      short8 af = *(const short8*)&lds[aoff[m] + (dy*58+dx)*16];
      #pragma unroll
      for (int n=0;n<4;n++)
        acc[m][n] = __builtin_amdgcn_mfma_f32_16x16x32_bf16(af, bfr[n], acc[m][n], 0,0,0);
    }
  }
  __syncthreads();

  float bias[4];
  #pragma unroll
  for (int n=0;n<4;n++){
    int ol = n*16 + (lane&15);
    bias[n] = bvv[(size_t)(head0 + z*2 + (ol>>5))*C_CH + (ol&31)];
  }
  #pragma unroll
  for (int m=0;m<7;m++){
    #pragma unroll
    for (int j=0;j<4;j++){
      int p = wid*112 + m*16 + (lane>>4)*4 + j;
      int yl = p/56, xl = p - (p/56)*56;
      int kl = xl >> 3;
      int off = yl*8 + (xl&7);
      #pragma unroll
      for (int n=0;n<4;n++){
        int ol = n*16 + (lane&15);
        int addr = ((ol>>5)*7 + kl)*4096 + (off*32 + (ol&31))*2;
        *(ushort_t*)&lds[addr] = f2bf(acc[m][n][j] + bias[n]);
      }
    }
  }
  __syncthreads();
  int key0 = t*NPATCH + pr*42 + xt*7;
  #pragma unroll
  for (int i=0;i<14;i++){
    int c = i*256 + tid;
    int hib = c / 1792;
    int rem = c - hib*1792;
    int kl = rem >> 8, dch = rem & 255;
    u16x8 v = *(const u16x8*)&lds[c*16];
    *(u16x8*)&Vu[((size_t)(z*2+hib)*NPAD + key0 + kl)*DD + dch*8] = v;
  }
}

// --------- Vu [head][key][dd'] -> Vt [head][dd'][key] ----------------------
__global__ __launch_bounds__(256) void vtranspose(
    const ushort_t* __restrict__ Vu, ushort_t* __restrict__ Vt)
{
  __shared__ ushort_t tile[64*68];
  int d0 = blockIdx.x*64;
  int k0 = blockIdx.y*64;
  const ushort_t* src = Vu + (size_t)blockIdx.z*NPAD*DD;
  ushort_t* dst = Vt + (size_t)blockIdx.z*DD*NPAD;
  int t = threadIdx.x;
  #pragma unroll
  for (int i=0;i<2;i++){
    int key = (t>>3) + i*32;
    int dd  = (t&7)*8;
    u16x8 v = *(const u16x8*)&src[(size_t)(k0+key)*DD + d0+dd];
    #pragma unroll
    for (int e=0;e<8;e++) tile[(dd+e)*68 + key] = v[e];
  }
  __syncthreads();
  #pragma unroll
  for (int i=0;i<2;i++){
    int dd  = (t>>3) + i*32;
    int key = (t&7)*8;
    u16x4 a = *(const u16x4*)&tile[dd*68 + key];
    u16x4 b = *(const u16x4*)&tile[dd*68 + key + 4];
    u16x8 v;
    v[0]=a[0]; v[1]=a[1]; v[2]=a[2]; v[3]=a[3];
    v[4]=b[0]; v[5]=b[1]; v[6]=b[2]; v[7]=b[3];
    *(u16x8*)&dst[(size_t)(d0+dd)*NPAD + k0+key] = v;
  }
}

// ======================= 8-phase 256x256 GEMM (R11, best measured) ==========
#define ABASE(b,kc) ((b)*32768 + (kc)*16384)
#define BBASE(b,kc) (65536 + (b)*32768 + (kc)*16384)

#define STG(dstb, Mat, t0, Rm1, ktc) { \
  int i0_ = tid;       int r0_ = i0_>>2; int c0_ = ((i0_&3) ^ ((r0_>>1)&3)); \
  gload16(Mat + (size_t)min(t0 + r0_, Rm1)*(size_t)K + (ktc) + c0_*8, \
          lds + (dstb) + (tid & ~63)*16); \
  int i1_ = 512 + tid; int r1_ = i1_>>2; int c1_ = ((i1_&3) ^ ((r1_>>1)&3)); \
  gload16(Mat + (size_t)min(t0 + r1_, Rm1)*(size_t)K + (ktc) + c1_*8, \
          lds + (dstb) + (512 + (tid & ~63))*16); }

#define RDAF(b,kc,mh) { _Pragma("unroll") \
  for (int m=0;m<4;m++) \
    af[m] = *(const short8*)(lds + ABASE(b,kc) + (wr*128 + (mh)*64 + m*16 + l15)*64 + rkB); }

#define RDBF(b,kc) { _Pragma("unroll") \
  for (int n=0;n<4;n++) \
    bf[n] = *(const short8*)(lds + BBASE(b,kc) + (wc*64 + n*16 + l15)*64 + rkB); }

#define LEADBAR() { __builtin_amdgcn_sched_barrier(0); \
  __builtin_amdgcn_s_barrier(); __builtin_amdgcn_sched_barrier(0); }

#define MFMA16(mh) { __builtin_amdgcn_s_setprio(1); \
  _Pragma("unroll") for (int m=0;m<4;m++){ \
    _Pragma("unroll") for (int n=0;n<4;n++) \
      acc[(mh)*4+m][n] = __builtin_amdgcn_mfma_f32_16x16x32_bf16(af[m], bf[n], acc[(mh)*4+m][n], 0,0,0); } \
  __builtin_amdgcn_s_setprio(0); }

#define TRAILBAR() { __builtin_amdgcn_sched_barrier(0); \
  __builtin_amdgcn_s_barrier(); __builtin_amdgcn_sched_barrier(0); }

#define GATEBAR(cond) { __builtin_amdgcn_sched_barrier(0); \
  if (cond) { asm volatile("s_waitcnt vmcnt(4)" ::: "memory"); } \
  else      { asm volatile("s_waitcnt vmcnt(0)" ::: "memory"); } \
  __builtin_amdgcn_s_barrier(); __builtin_amdgcn_sched_barrier(0); }

template<int MODE>
__global__ __launch_bounds__(512) void gemm8p(
    const ushort_t* __restrict__ A, const ushort_t* __restrict__ B,
    float* __restrict__ C, float* __restrict__ Out,
    int K, int Am1, int Bm1, size_t aStr, size_t bStr, int head0)
{
  __shared__ __align__(16) char lds[131072];
  int tid = threadIdx.x, lane = tid & 63, wid = tid >> 6;

  // bijective XCD swizzle (nwg % 8 == 0 for both grids)
  int gx = gridDim.x, gy = gridDim.y;
  int nwg = gx*gy*gridDim.z;
  int id  = (blockIdx.z*gy + blockIdx.y)*gx + blockIdx.x;
  int swz = (id & 7)*(nwg >> 3) + (id >> 3);
  int bx = swz % gx; int tmp = swz / gx;
  int by = tmp % gy; int bz = tmp / gy;

  const ushort_t* Ab = A + (size_t)bz*aStr;
  const ushort_t* Bb = B + (size_t)bz*bStr;
  int row0 = by*256, col0 = bx*256;
  int wr = wid >> 2, wc = wid & 3;           // 2M x 4N waves; wave = 128M x 64N
  int l15 = lane & 15;
  int rkB = (((lane>>4) ^ ((l15>>1)&3)) * 16);

  f32x4 acc[8][4] = {};
  int NT = K >> 6;          // BK=64 tiles (32 or 38, both even)
  int NI = NT >> 1;

  STG(ABASE(0,0), Ab, row0, Am1, 0)
  STG(BBASE(0,0), Bb, col0, Bm1, 0)
  STG(ABASE(0,1), Ab, row0, Am1, 32)
  STG(BBASE(0,1), Bb, col0, Bm1, 32)
  STG(ABASE(1,0), Ab, row0, Am1, 64)
  STG(BBASE(1,0), Bb, col0, Bm1, 64)
  __builtin_amdgcn_sched_barrier(0);
  asm volatile("s_waitcnt vmcnt(4)" ::: "memory");
  __builtin_amdgcn_s_barrier();
  __builtin_amdgcn_sched_barrier(0);

  #pragma unroll 1
  for (int it = 0; it < NI; ++it){
    int T1k = (2*it+1) << 6;
    int T2k = (2*it+2) << 6;
    int T3k = (2*it+3) << 6;
    bool s2 = (2*it+2 < NT), s3 = (2*it+3 < NT);
    short8 af[4], bf[4];

    RDAF(0,0,0) RDBF(0,0)
    STG(ABASE(1,1), Ab, row0, Am1, T1k+32)
    LEADBAR() MFMA16(0) TRAILBAR()
    RDAF(0,0,1)
    STG(BBASE(1,1), Bb, col0, Bm1, T1k+32)
    LEADBAR() MFMA16(1) TRAILBAR()
    RDAF(0,1,0) RDBF(0,1)
    if (s2) STG(ABASE(0,0), Ab, row0, Am1, T2k)
    LEADBAR() MFMA16(0) TRAILBAR()
    RDAF(0,1,1)
    if (s2) STG(BBASE(0,0), Bb, col0, Bm1, T2k)
    LEADBAR() MFMA16(1)
    GATEBAR(s2)
    RDAF(1,0,0) RDBF(1,0)
    if (s2) STG(ABASE(0,1), Ab, row0, Am1, T2k+32)
    LEADBAR() MFMA16(0) TRAILBAR()
    RDAF(1,0,1)
    if (s2) STG(BBASE(0,1), Bb, col0, Bm1, T2k+32)
    LEADBAR() MFMA16(1) TRAILBAR()
    RDAF(1,1,0) RDBF(1,1)
    if (s3) STG(ABASE(1,0), Ab, row0, Am1, T3k)
    LEADBAR() MFMA16(0) TRAILBAR()
    RDAF(1,1,1)
    if (s3) STG(BBASE(1,0), Bb, col0, Bm1, T3k)
    LEADBAR() MFMA16(1)
    GATEBAR(s3)
  }

  int rb0 = row0 + wr*128 + (lane>>4)*4;
  int cb0 = col0 + wc*64 + l15;
  if (MODE == 0){
    float* Cb = C + (size_t)bz*NPAD*(size_t)NPAD;
    #pragma unroll
    for (int M=0;M<8;M++)
      #pragma unroll
      for (int n=0;n<4;n++){
        int col = cb0 + n*16;
        if (col < NPAD)
          #pragma unroll
          for (int j=0;j<4;j++){
            int row = rb0 + M*16 + j;
            if (row < NPAD)
              Cb[(size_t)row*NPAD + col] = acc[M][n][j];
          }
      }
  } else {
    int head = head0 + bz;
    #pragma unroll
    for (int M=0;M<8;M++){
      #pragma unroll
      for (int j=0;j<4;j++){
        int q = rb0 + M*16 + j;
        if (q < NQ){
          int t = q / NPATCH;
          int p = q - t*NPATCH;
          int hi = p / 42, wi = p - hi*42;
          #pragma unroll
          for (int n=0;n<4;n++){
            int dd = cb0 + n*16;            // dd' = (pi*8+pj)*32 + cch
            int cch = dd & 31;
            int off = dd >> 5;
            int pi = off >> 3, pj = off & 7;
            int yy = hi*8 + pi, xx = wi*8 + pj;
            Out[(((size_t)t*C_CH + cch)*H_IMG + yy)*WOUT + (size_t)head*W_IMG + xx]
              = acc[M][n][j];
          }
        }
      }
    }
  }
}

// ------------- row softmax: S f32 -> P bf16 (vectorized, G13) ---------------
// Runs only on the NQ valid rows; Pm pad rows feed masked outputs only.
__global__ __launch_bounds__(256) void softmax_rows(
    const float* __restrict__ S, ushort_t* __restrict__ Pm)
{
  const float* row = S + ((size_t)blockIdx.y*NPAD + blockIdx.x)*NPAD;
  ushort_t* prow = Pm + ((size_t)blockIdx.y*NPAD + blockIdx.x)*NPAD;
  int tid = threadIdx.x;
  __shared__ float red[4];
  const f32x4* row4 = (const f32x4*)row;

  bool h2 = (512 + tid) < 588;
  f32x4 v0 = row4[tid];
  f32x4 v1 = row4[256 + tid];
  f32x4 v2 = {-3.0e38f, -3.0e38f, -3.0e38f, -3.0e38f};
  if (h2) v2 = row4[512 + tid];

  float mx = -3.0e38f;
  #pragma unroll
  for (int e=0;e<4;e++) mx = fmaxf(mx, fmaxf(v0[e], fmaxf(v1[e], v2[e])));
  #pragma unroll
  for (int o=32;o;o>>=1) mx = fmaxf(mx, __shfl_xor(mx, o));
  if ((tid&63)==0) red[tid>>6] = mx;
  __syncthreads();
  mx = fmaxf(fmaxf(red[0],red[1]), fmaxf(red[2],red[3]));
  __syncthreads();

  f32x4 e0, e1, e2 = {0.f,0.f,0.f,0.f};
  float s = 0.f;
  #pragma unroll
  for (int e=0;e<4;e++){ e0[e] = __expf((v0[e]-mx)*SM_SCALE); s += e0[e]; }
  #pragma unroll
  for (int e=0;e<4;e++){ e1[e] = __expf((v1[e]-mx)*SM_SCALE); s += e1[e]; }
  if (h2){
    #pragma unroll
    for (int e=0;e<4;e++){ e2[e] = __expf((v2[e]-mx)*SM_SCALE); s += e2[e]; }
  }
  #pragma unroll
  for (int o=32;o;o>>=1) s += __shfl_xor(s, o);
  if ((tid&63)==0) red[tid>>6] = s;
  __syncthreads();
  s = (red[0]+red[1]) + (red[2]+red[3]);
  float inv = 1.0f / s;

  u16x4 o0, o1;
  #pragma unroll
  for (int e=0;e<4;e++) o0[e] = f2bf(e0[e]*inv);
  #pragma unroll
  for (int e=0;e<4;e++) o1[e] = f2bf(e1[e]*inv);
  *(u16x4*)&prow[tid*4]        = o0;
  *(u16x4*)&prow[1024 + tid*4] = o1;
  if (h2){
    u16x4 o2;
    #pragma unroll
    for (int e=0;e<4;e++) o2[e] = f2bf(e2[e]*inv);
    *(u16x4*)&prow[2048 + tid*4] = o2;
  } else if (512 + tid < 608){
    u16x4 z = {0,0,0,0};
    *(u16x4*)&prow[2048 + tid*4] = z;   // pad cols 2352..2431 (must be 0)
  }
}

// ------------------------------------------------------------------ host ----
extern "C" void kernel_launch(void* const* d_in, const int* in_sizes, int n_in,
                              void* d_out, int out_size, void* d_ws, size_t ws_size,
                              hipStream_t stream)
{
  const float* query = (const float*)d_in[0];
  const float* key_  = (const float*)d_in[1];
  const float* value = (const float*)d_in[2];
  const float* Wq = (const float*)d_in[3];
  const float* bq = (const float*)d_in[4];
  const float* Wk = (const float*)d_in[5];
  const float* bk = (const float*)d_in[6];
  const float* Wv = (const float*)d_in[7];
  const float* bv = (const float*)d_in[8];
  float* out = (float*)d_out;

  const size_t szU = (size_t)NPAD*DD;
  const size_t szS = (size_t)NPAD*NPAD;
  const size_t perHeadB = 3*szU*sizeof(ushort_t) + szS*sizeof(float) + szS*sizeof(ushort_t);

  int nh = (ws_size >= 4*perHeadB) ? 4 : 2;

  for (int h0 = 0; h0 < NH; h0 += nh){
    char* p = (char*)d_ws;
    ushort_t* Qu = (ushort_t*)p; p += nh*szU*sizeof(ushort_t);
    ushort_t* Ku = (ushort_t*)p; p += nh*szU*sizeof(ushort_t);
    ushort_t* Vu = (ushort_t*)p; p += nh*szU*sizeof(ushort_t);
    float*    S  = (float*)p;    p += nh*szS*sizeof(float);
    ushort_t* Pm = (ushort_t*)p;
    ushort_t* inCL = (ushort_t*)S;                 // S region dead until gemm_qk
    ushort_t* Wb   = inCL + (size_t)PIX_T*C_CH;
    ushort_t* Vt   = Qu;                           // Qu dead after gemm_qk

    int prepItems = PIX_T + 9*128*32 + nh*(80*DD/8);
    prep_all<<<dim3((prepItems + 255)/256), dim3(256), 0, stream>>>(
        value, Wv, inCL, Wb, Vu, nh);
    dwconv_unfold<<<dim3(2352), dim3(256), 0, stream>>>(query, Wq, bq, Qu, h0, nh);
    dwconv_unfold<<<dim3(2352), dim3(256), 0, stream>>>(key_,  Wk, bk, Ku, h0, nh);
    vconv_mfma<<<dim3(6, 56, nh/2), dim3(256), 0, stream>>>(inCL, Wb, bv, Vu, h0);
    // QK^T: A=Qu, B=Ku, K=DD; grid 10x10x4 = 400 (%8==0)
    gemm8p<0><<<dim3(10, 10, nh), dim3(512), 0, stream>>>(
        Qu, Ku, S, nullptr, DD, NPAD-1, NPAD-1, szU, szU, h0);
    vtranspose<<<dim3(32, 38, nh), dim3(256), 0, stream>>>(Vu, Vt);
    softmax_rows<<<dim3(NQ, nh), dim3(256), 0, stream>>>(S, Pm);
    // PV: A=Pm [NPAD][NPAD], B=Vt [DD][NPAD], K=NPAD; grid 8x10x4 = 320
    gemm8p<1><<<dim3(8, 10, nh), dim3(512), 0, stream>>>(
        Pm, Vt, nullptr, out, NPAD, NPAD-1, DD-1, szS, szU, h0);
  }
}

// Round 15
// 466.147 us; speedup vs baseline: 1.0996x; 1.0164x over previous
//
#include <hip/hip_runtime.h>
#include <hip/hip_bf16.h>

#define T_FR 2
#define C_CH 32
#define H_IMG 224
#define W_IMG 336
#define NH 4
#define NPATCH 1176
#define NQ 2352
#define NPAD 2432
#define DD 2048
#define WOUT (W_IMG*NH)
#define SM_SCALE 0.6629126073623885f   // 30/sqrt(2048)
#define PIX_F (H_IMG*W_IMG)            // 75264
#define PIX_T (T_FR*PIX_F)             // 150528

typedef __attribute__((ext_vector_type(4))) float f32x4;
typedef __attribute__((ext_vector_type(8))) short short8;
typedef unsigned short ushort_t;
typedef __attribute__((ext_vector_type(4))) unsigned short u16x4;
typedef __attribute__((ext_vector_type(8))) unsigned short u16x8;

__device__ inline ushort_t f2bf(float x){
  union { float f; unsigned int u; } v; v.f = x;
  unsigned int r = v.u + 0x7fffu + ((v.u >> 16) & 1u);
  return (ushort_t)(r >> 16);
}

__device__ inline void gload16(const void* g, void* l){
  __builtin_amdgcn_global_load_lds(
      (const __attribute__((address_space(1))) void*)g,
      (__attribute__((address_space(3))) void*)l,
      16, 0, 0);
}

// ---- merged prep: V->channels-last bf16 | Wv->Wb bf16 | Vu pad-row zero ----
__global__ __launch_bounds__(256) void prep_all(
    const float* __restrict__ value, const float* __restrict__ Wv,
    ushort_t* __restrict__ inCL, ushort_t* __restrict__ Wb,
    ushort_t* __restrict__ Vu, int nh)
{
  int id = blockIdx.x*256 + threadIdx.x;
  if (id < PIX_T){
    int t = id / PIX_F;
    int p = id - t*PIX_F;
    const float* src = value + (size_t)t*C_CH*PIX_F + p;
    #pragma unroll
    for (int oct=0; oct<4; oct++){
      u16x8 u;
      #pragma unroll
      for (int e=0; e<8; e++)
        u[e] = f2bf(src[(size_t)(oct*8+e)*PIX_F]);
      *(u16x8*)&inCL[(size_t)id*C_CH + oct*8] = u;
    }
    return;
  }
  id -= PIX_T;
  if (id < 9*128*32){
    int tap = id >> 12;
    int og  = (id >> 5) & 127;
    int cc  = id & 31;
    Wb[id] = f2bf(Wv[(size_t)og*288 + cc*9 + tap]);
    return;
  }
  id -= 9*128*32;
  const int perH = 80*DD/8;                 // 20480 u16x8 items per head
  if (id < nh*perH){
    int h = id / perH;
    int e = id - h*perH;
    u16x8 z = {0,0,0,0,0,0,0,0};
    *(u16x8*)&Vu[((size_t)h*NPAD + NQ)*DD + (size_t)e*8] = z;
  }
}

// -- depthwise 3x3 conv + unfold; grid.y selects {Q,K}; all heads per thread -
__global__ __launch_bounds__(256) void dwconv_unfold(
    const float* __restrict__ inQ, const float* __restrict__ inK,
    const float* __restrict__ Wq, const float* __restrict__ bq,
    const float* __restrict__ Wk, const float* __restrict__ bk,
    ushort_t* __restrict__ Qu, ushort_t* __restrict__ Ku,
    int head0, int nh)
{
  const float* in = (blockIdx.y == 0) ? inQ : inK;
  const float* Wd = (blockIdx.y == 0) ? Wq : Wk;
  const float* bd = (blockIdx.y == 0) ? bq : bk;
  ushort_t* outU  = (blockIdx.y == 0) ? Qu : Ku;

  int id = blockIdx.x*256 + threadIdx.x;       // 602112 total
  int cc = id & 31;
  int rest = id >> 5;
  int xseg = rest % 42;
  rest /= 42;
  int y = rest % H_IMG;
  int t = rest / H_IMG;

  const float* src = in + ((size_t)(t*C_CH + cc)*H_IMG)*W_IMG;
  int x0 = xseg*8;

  float r0[10], r1[10], r2[10];
  #pragma unroll
  for (int j=0;j<10;j++){
    int xx = x0 + j - 1;
    bool xok = (xx>=0) && (xx<W_IMG);
    r0[j] = (xok && y>0)         ? src[(size_t)(y-1)*W_IMG+xx] : 0.f;
    r1[j] = (xok)                ? src[(size_t)y*W_IMG+xx]     : 0.f;
    r2[j] = (xok && y<H_IMG-1)   ? src[(size_t)(y+1)*W_IMG+xx] : 0.f;
  }
  int qrow = t*NPATCH + (y>>3)*42 + xseg;
  int dcol = (y&7)*256 + cc*8;

  for (int h = 0; h < nh; ++h){
    const float* w = Wd + ((size_t)(head0+h)*C_CH + cc)*9;
    float w0=w[0],w1=w[1],w2=w[2],w3=w[3],w4=w[4],w5=w[5],w6=w[6],w7=w[7],w8=w[8];
    float bias = bd[(size_t)(head0+h)*C_CH + cc];
    u16x8 res;
    #pragma unroll
    for (int j=0;j<8;j++){
      float a = bias;
      a += r0[j]*w0 + r0[j+1]*w1 + r0[j+2]*w2;
      a += r1[j]*w3 + r1[j+1]*w4 + r1[j+2]*w5;
      a += r2[j]*w6 + r2[j+1]*w7 + r2[j+2]*w8;
      res[j] = f2bf(a);
    }
    *(u16x8*)&outU[((size_t)h*NPAD + qrow)*DD + dcol] = res;
  }
}

// --------- dense V conv as implicit MFMA GEMM + coalesced Vu write ---------
#define VA_HALO 0
#define VA_BS   37120
#define V_LDS   73984

__global__ __launch_bounds__(256) void vconv_mfma(
    const ushort_t* __restrict__ inCL, const ushort_t* __restrict__ Wb,
    const float* __restrict__ bvv, ushort_t* __restrict__ Vu, int head0)
{
  __shared__ __align__(16) char lds[V_LDS];
  int xt = blockIdx.x;
  int pr_g = blockIdx.y;
  int z  = blockIdx.z;
  int t  = pr_g / 28, pr = pr_g - t*28;
  int x0 = xt*56, y0 = pr*8;
  int tid = threadIdx.x, lane = tid & 63, wid = tid >> 6;

  for (int i = tid; i < 580; i += 256){
    int ly = i/58, lx = i - (i/58)*58;
    int gy = y0 - 1 + ly, gx = x0 - 1 + lx;
    u16x8 v0={},v1={},v2={},v3={};
    if (gy>=0 && gy<H_IMG && gx>=0 && gx<W_IMG){
      const u16x8* s = (const u16x8*)&inCL[((size_t)t*PIX_F + gy*W_IMG + gx)*C_CH];
      v0=s[0]; v1=s[1]; v2=s[2]; v3=s[3];
    }
    *(u16x8*)&lds[VA_HALO + 0*9280 + i*16] = v0;
    *(u16x8*)&lds[VA_HALO + 1*9280 + i*16] = v1;
    *(u16x8*)&lds[VA_HALO + 2*9280 + i*16] = v2;
    *(u16x8*)&lds[VA_HALO + 3*9280 + i*16] = v3;
  }
  for (int i = tid; i < 576; i += 256){
    int tap = i/64, ol = i - (i/64)*64;
    const u16x8* s = (const u16x8*)&Wb[((size_t)tap*128 + head0*32 + z*64 + ol)*C_CH];
    #pragma unroll
    for (int oct=0; oct<4; oct++)
      *(u16x8*)&lds[VA_BS + tap*4096 + ol*64 + ((oct^(ol&3))<<4)] = s[oct];
  }
  __syncthreads();

  int aoff[7];
  #pragma unroll
  for (int m=0;m<7;m++){
    int pm = wid*112 + m*16 + (lane&15);
    int yl = pm/56, xl = pm - yl*56;
    aoff[m] = VA_HALO + (lane>>4)*9280 + (yl*58 + xl)*16;
  }

  f32x4 acc[7][4] = {};
  #pragma unroll
  for (int tap=0; tap<9; tap++){
    const int dy = tap/3, dx = tap - (tap/3)*3;
    short8 bfr[4];
    #pragma unroll
    for (int n=0;n<4;n++){
      int ol = n*16 + (lane&15);
      bfr[n] = *(const short8*)&lds[VA_BS + tap*4096 + ol*64 + ((((lane>>4))^(ol&3))<<4)];
    }
    #pragma unroll
    for (int m=0;m<7;m++){
      short8 af = *(const short8*)&lds[aoff[m] + (dy*58+dx)*16];
      #pragma unroll
      for (int n=0;n<4;n++)
        acc[m][n] = __builtin_amdgcn_mfma_f32_16x16x32_bf16(af, bfr[n], acc[m][n], 0,0,0);
    }
  }
  __syncthreads();

  float bias[4];
  #pragma unroll
  for (int n=0;n<4;n++){
    int ol = n*16 + (lane&15);
    bias[n] = bvv[(size_t)(head0 + z*2 + (ol>>5))*C_CH + (ol&31)];
  }
  #pragma unroll
  for (int m=0;m<7;m++){
    #pragma unroll
    for (int j=0;j<4;j++){
      int p = wid*112 + m*16 + (lane>>4)*4 + j;
      int yl = p/56, xl = p - (p/56)*56;
      int kl = xl >> 3;
      int off = yl*8 + (xl&7);
      #pragma unroll
      for (int n=0;n<4;n++){
        int ol = n*16 + (lane&15);
        int addr = ((ol>>5)*7 + kl)*4096 + (off*32 + (ol&31))*2;
        *(ushort_t*)&lds[addr] = f2bf(acc[m][n][j] + bias[n]);
      }
    }
  }
  __syncthreads();
  int key0 = t*NPATCH + pr*42 + xt*7;
  #pragma unroll
  for (int i=0;i<14;i++){
    int c = i*256 + tid;
    int hib = c / 1792;
    int rem = c - hib*1792;
    int kl = rem >> 8, dch = rem & 255;
    u16x8 v = *(const u16x8*)&lds[c*16];
    *(u16x8*)&Vu[((size_t)(z*2+hib)*NPAD + key0 + kl)*DD + dch*8] = v;
  }
}

// --------- Vu [head][key][dd'] -> Vt [head][dd'][key] ----------------------
__global__ __launch_bounds__(256) void vtranspose(
    const ushort_t* __restrict__ Vu, ushort_t* __restrict__ Vt)
{
  __shared__ ushort_t tile[64*68];
  int d0 = blockIdx.x*64;
  int k0 = blockIdx.y*64;
  const ushort_t* src = Vu + (size_t)blockIdx.z*NPAD*DD;
  ushort_t* dst = Vt + (size_t)blockIdx.z*DD*NPAD;
  int t = threadIdx.x;
  #pragma unroll
  for (int i=0;i<2;i++){
    int key = (t>>3) + i*32;
    int dd  = (t&7)*8;
    u16x8 v = *(const u16x8*)&src[(size_t)(k0+key)*DD + d0+dd];
    #pragma unroll
    for (int e=0;e<8;e++) tile[(dd+e)*68 + key] = v[e];
  }
  __syncthreads();
  #pragma unroll
  for (int i=0;i<2;i++){
    int dd  = (t>>3) + i*32;
    int key = (t&7)*8;
    u16x4 a = *(const u16x4*)&tile[dd*68 + key];
    u16x4 b = *(const u16x4*)&tile[dd*68 + key + 4];
    u16x8 v;
    v[0]=a[0]; v[1]=a[1]; v[2]=a[2]; v[3]=a[3];
    v[4]=b[0]; v[5]=b[1]; v[6]=b[2]; v[7]=b[3];
    *(u16x8*)&dst[(size_t)(d0+dd)*NPAD + k0+key] = v;
  }
}

// ======================= 8-phase 256x256 GEMM (R11/R14, best measured) ======
// Structural entitlement note: acc(128 AGPR)+VGPR = 256 unified regs/wave ->
// 1 block/CU; LDS read dup (A x4, B x2) = 192KB/BK64-tile ~ 565cy/phase vs
// 155cy MFMA, serialized (no reg headroom for frag dbuf) -> ~25-30% MfmaUtil
// ceiling at this shape; grids 400/320 at 1 blk/CU -> 78%/62.5% tails.
#define ABASE(b,kc) ((b)*32768 + (kc)*16384)
#define BBASE(b,kc) (65536 + (b)*32768 + (kc)*16384)

#define STG(dstb, Mat, t0, Rm1, ktc) { \
  int i0_ = tid;       int r0_ = i0_>>2; int c0_ = ((i0_&3) ^ ((r0_>>1)&3)); \
  gload16(Mat + (size_t)min(t0 + r0_, Rm1)*(size_t)K + (ktc) + c0_*8, \
          lds + (dstb) + (tid & ~63)*16); \
  int i1_ = 512 + tid; int r1_ = i1_>>2; int c1_ = ((i1_&3) ^ ((r1_>>1)&3)); \
  gload16(Mat + (size_t)min(t0 + r1_, Rm1)*(size_t)K + (ktc) + c1_*8, \
          lds + (dstb) + (512 + (tid & ~63))*16); }

#define RDAF(b,kc,mh) { _Pragma("unroll") \
  for (int m=0;m<4;m++) \
    af[m] = *(const short8*)(lds + ABASE(b,kc) + (wr*128 + (mh)*64 + m*16 + l15)*64 + rkB); }

#define RDBF(b,kc) { _Pragma("unroll") \
  for (int n=0;n<4;n++) \
    bf[n] = *(const short8*)(lds + BBASE(b,kc) + (wc*64 + n*16 + l15)*64 + rkB); }

#define LEADBAR() { __builtin_amdgcn_sched_barrier(0); \
  __builtin_amdgcn_s_barrier(); __builtin_amdgcn_sched_barrier(0); }

#define MFMA16(mh) { __builtin_amdgcn_s_setprio(1); \
  _Pragma("unroll") for (int m=0;m<4;m++){ \
    _Pragma("unroll") for (int n=0;n<4;n++) \
      acc[(mh)*4+m][n] = __builtin_amdgcn_mfma_f32_16x16x32_bf16(af[m], bf[n], acc[(mh)*4+m][n], 0,0,0); } \
  __builtin_amdgcn_s_setprio(0); }

#define TRAILBAR() { __builtin_amdgcn_sched_barrier(0); \
  __builtin_amdgcn_s_barrier(); __builtin_amdgcn_sched_barrier(0); }

#define GATEBAR(cond) { __builtin_amdgcn_sched_barrier(0); \
  if (cond) { asm volatile("s_waitcnt vmcnt(4)" ::: "memory"); } \
  else      { asm volatile("s_waitcnt vmcnt(0)" ::: "memory"); } \
  __builtin_amdgcn_s_barrier(); __builtin_amdgcn_sched_barrier(0); }

template<int MODE>
__global__ __launch_bounds__(512) void gemm8p(
    const ushort_t* __restrict__ A, const ushort_t* __restrict__ B,
    float* __restrict__ C, float* __restrict__ Out,
    int K, int Am1, int Bm1, size_t aStr, size_t bStr, int head0)
{
  __shared__ __align__(16) char lds[131072];
  int tid = threadIdx.x, lane = tid & 63, wid = tid >> 6;

  int gx = gridDim.x, gy = gridDim.y;
  int nwg = gx*gy*gridDim.z;
  int id  = (blockIdx.z*gy + blockIdx.y)*gx + blockIdx.x;
  int swz = (id & 7)*(nwg >> 3) + (id >> 3);
  int bx = swz % gx; int tmp = swz / gx;
  int by = tmp % gy; int bz = tmp / gy;

  const ushort_t* Ab = A + (size_t)bz*aStr;
  const ushort_t* Bb = B + (size_t)bz*bStr;
  int row0 = by*256, col0 = bx*256;
  int wr = wid >> 2, wc = wid & 3;
  int l15 = lane & 15;
  int rkB = (((lane>>4) ^ ((l15>>1)&3)) * 16);

  f32x4 acc[8][4] = {};
  int NT = K >> 6;
  int NI = NT >> 1;

  STG(ABASE(0,0), Ab, row0, Am1, 0)
  STG(BBASE(0,0), Bb, col0, Bm1, 0)
  STG(ABASE(0,1), Ab, row0, Am1, 32)
  STG(BBASE(0,1), Bb, col0, Bm1, 32)
  STG(ABASE(1,0), Ab, row0, Am1, 64)
  STG(BBASE(1,0), Bb, col0, Bm1, 64)
  __builtin_amdgcn_sched_barrier(0);
  asm volatile("s_waitcnt vmcnt(4)" ::: "memory");
  __builtin_amdgcn_s_barrier();
  __builtin_amdgcn_sched_barrier(0);

  #pragma unroll 1
  for (int it = 0; it < NI; ++it){
    int T1k = (2*it+1) << 6;
    int T2k = (2*it+2) << 6;
    int T3k = (2*it+3) << 6;
    bool s2 = (2*it+2 < NT), s3 = (2*it+3 < NT);
    short8 af[4], bf[4];

    RDAF(0,0,0) RDBF(0,0)
    STG(ABASE(1,1), Ab, row0, Am1, T1k+32)
    LEADBAR() MFMA16(0) TRAILBAR()
    RDAF(0,0,1)
    STG(BBASE(1,1), Bb, col0, Bm1, T1k+32)
    LEADBAR() MFMA16(1) TRAILBAR()
    RDAF(0,1,0) RDBF(0,1)
    if (s2) STG(ABASE(0,0), Ab, row0, Am1, T2k)
    LEADBAR() MFMA16(0) TRAILBAR()
    RDAF(0,1,1)
    if (s2) STG(BBASE(0,0), Bb, col0, Bm1, T2k)
    LEADBAR() MFMA16(1)
    GATEBAR(s2)
    RDAF(1,0,0) RDBF(1,0)
    if (s2) STG(ABASE(0,1), Ab, row0, Am1, T2k+32)
    LEADBAR() MFMA16(0) TRAILBAR()
    RDAF(1,0,1)
    if (s2) STG(BBASE(0,1), Bb, col0, Bm1, T2k+32)
    LEADBAR() MFMA16(1) TRAILBAR()
    RDAF(1,1,0) RDBF(1,1)
    if (s3) STG(ABASE(1,0), Ab, row0, Am1, T3k)
    LEADBAR() MFMA16(0) TRAILBAR()
    RDAF(1,1,1)
    if (s3) STG(BBASE(1,0), Bb, col0, Bm1, T3k)
    LEADBAR() MFMA16(1)
    GATEBAR(s3)
  }

  int rb0 = row0 + wr*128 + (lane>>4)*4;
  int cb0 = col0 + wc*64 + l15;
  if (MODE == 0){
    float* Cb = C + (size_t)bz*NPAD*(size_t)NPAD;
    #pragma unroll
    for (int M=0;M<8;M++)
      #pragma unroll
      for (int n=0;n<4;n++){
        int col = cb0 + n*16;
        if (col < NPAD)
          #pragma unroll
          for (int j=0;j<4;j++){
            int row = rb0 + M*16 + j;
            if (row < NPAD)
              Cb[(size_t)row*NPAD + col] = acc[M][n][j];
          }
      }
  } else {
    int head = head0 + bz;
    #pragma unroll
    for (int M=0;M<8;M++){
      #pragma unroll
      for (int j=0;j<4;j++){
        int q = rb0 + M*16 + j;
        if (q < NQ){
          int t = q / NPATCH;
          int p = q - t*NPATCH;
          int hi = p / 42, wi = p - hi*42;
          #pragma unroll
          for (int n=0;n<4;n++){
            int dd = cb0 + n*16;            // dd' = (pi*8+pj)*32 + cch
            int cch = dd & 31;
            int off = dd >> 5;
            int pi = off >> 3, pj = off & 7;
            int yy = hi*8 + pi, xx = wi*8 + pj;
            Out[(((size_t)t*C_CH + cch)*H_IMG + yy)*WOUT + (size_t)head*W_IMG + xx]
              = acc[M][n][j];
          }
        }
      }
    }
  }
}

// ------------- row softmax: S f32 -> P bf16 (vectorized, G13) ---------------
__global__ __launch_bounds__(256) void softmax_rows(
    const float* __restrict__ S, ushort_t* __restrict__ Pm)
{
  const float* row = S + ((size_t)blockIdx.y*NPAD + blockIdx.x)*NPAD;
  ushort_t* prow = Pm + ((size_t)blockIdx.y*NPAD + blockIdx.x)*NPAD;
  int tid = threadIdx.x;
  __shared__ float red[4];
  const f32x4* row4 = (const f32x4*)row;

  bool h2 = (512 + tid) < 588;
  f32x4 v0 = row4[tid];
  f32x4 v1 = row4[256 + tid];
  f32x4 v2 = {-3.0e38f, -3.0e38f, -3.0e38f, -3.0e38f};
  if (h2) v2 = row4[512 + tid];

  float mx = -3.0e38f;
  #pragma unroll
  for (int e=0;e<4;e++) mx = fmaxf(mx, fmaxf(v0[e], fmaxf(v1[e], v2[e])));
  #pragma unroll
  for (int o=32;o;o>>=1) mx = fmaxf(mx, __shfl_xor(mx, o));
  if ((tid&63)==0) red[tid>>6] = mx;
  __syncthreads();
  mx = fmaxf(fmaxf(red[0],red[1]), fmaxf(red[2],red[3]));
  __syncthreads();

  f32x4 e0, e1, e2 = {0.f,0.f,0.f,0.f};
  float s = 0.f;
  #pragma unroll
  for (int e=0;e<4;e++){ e0[e] = __expf((v0[e]-mx)*SM_SCALE); s += e0[e]; }
  #pragma unroll
  for (int e=0;e<4;e++){ e1[e] = __expf((v1[e]-mx)*SM_SCALE); s += e1[e]; }
  if (h2){
    #pragma unroll
    for (int e=0;e<4;e++){ e2[e] = __expf((v2[e]-mx)*SM_SCALE); s += e2[e]; }
  }
  #pragma unroll
  for (int o=32;o;o>>=1) s += __shfl_xor(s, o);
  if ((tid&63)==0) red[tid>>6] = s;
  __syncthreads();
  s = (red[0]+red[1]) + (red[2]+red[3]);
  float inv = 1.0f / s;

  u16x4 o0, o1;
  #pragma unroll
  for (int e=0;e<4;e++) o0[e] = f2bf(e0[e]*inv);
  #pragma unroll
  for (int e=0;e<4;e++) o1[e] = f2bf(e1[e]*inv);
  *(u16x4*)&prow[tid*4]        = o0;
  *(u16x4*)&prow[1024 + tid*4] = o1;
  if (h2){
    u16x4 o2;
    #pragma unroll
    for (int e=0;e<4;e++) o2[e] = f2bf(e2[e]*inv);
    *(u16x4*)&prow[2048 + tid*4] = o2;
  } else if (512 + tid < 608){
    u16x4 z = {0,0,0,0};
    *(u16x4*)&prow[2048 + tid*4] = z;   // pad cols 2352..2431 (must be 0)
  }
}

// ------------------------------------------------------------------ host ----
extern "C" void kernel_launch(void* const* d_in, const int* in_sizes, int n_in,
                              void* d_out, int out_size, void* d_ws, size_t ws_size,
                              hipStream_t stream)
{
  const float* query = (const float*)d_in[0];
  const float* key_  = (const float*)d_in[1];
  const float* value = (const float*)d_in[2];
  const float* Wq = (const float*)d_in[3];
  const float* bq = (const float*)d_in[4];
  const float* Wk = (const float*)d_in[5];
  const float* bk = (const float*)d_in[6];
  const float* Wv = (const float*)d_in[7];
  const float* bv = (const float*)d_in[8];
  float* out = (float*)d_out;

  const size_t szU = (size_t)NPAD*DD;
  const size_t szS = (size_t)NPAD*NPAD;
  const size_t perHeadB = 3*szU*sizeof(ushort_t) + szS*sizeof(float) + szS*sizeof(ushort_t);

  int nh = (ws_size >= 4*perHeadB) ? 4 : 2;

  for (int h0 = 0; h0 < NH; h0 += nh){
    char* p = (char*)d_ws;
    ushort_t* Qu = (ushort_t*)p; p += nh*szU*sizeof(ushort_t);
    ushort_t* Ku = (ushort_t*)p; p += nh*szU*sizeof(ushort_t);
    ushort_t* Vu = (ushort_t*)p; p += nh*szU*sizeof(ushort_t);
    float*    S  = (float*)p;    p += nh*szS*sizeof(float);
    ushort_t* Pm = (ushort_t*)p;
    ushort_t* inCL = (ushort_t*)S;                 // S region dead until gemm_qk
    ushort_t* Wb   = inCL + (size_t)PIX_T*C_CH;
    ushort_t* Vt   = Qu;                           // Qu dead after gemm_qk

    int prepItems = PIX_T + 9*128*32 + nh*(80*DD/8);
    prep_all<<<dim3((prepItems + 255)/256), dim3(256), 0, stream>>>(
        value, Wv, inCL, Wb, Vu, nh);
    dwconv_unfold<<<dim3(2352, 2), dim3(256), 0, stream>>>(
        query, key_, Wq, bq, Wk, bk, Qu, Ku, h0, nh);
    vconv_mfma<<<dim3(6, 56, nh/2), dim3(256), 0, stream>>>(inCL, Wb, bv, Vu, h0);
    // QK^T: A=Qu, B=Ku, K=DD; grid 10x10x4 = 400 (%8==0)
    gemm8p<0><<<dim3(10, 10, nh), dim3(512), 0, stream>>>(
        Qu, Ku, S, nullptr, DD, NPAD-1, NPAD-1, szU, szU, h0);
    vtranspose<<<dim3(32, 38, nh), dim3(256), 0, stream>>>(Vu, Vt);
    softmax_rows<<<dim3(NQ, nh), dim3(256), 0, stream>>>(S, Pm);
    // PV: A=Pm [NPAD][NPAD], B=Vt [DD][NPAD], K=NPAD; grid 8x10x4 = 320
    gemm8p<1><<<dim3(8, 10, nh), dim3(512), 0, stream>>>(
        Pm, Vt, nullptr, out, NPAD, NPAD-1, DD-1, szS, szU, h0);
  }
}